// Round 3
// baseline (518.547 us; speedup 1.0000x reference)
//
#include <hip/hip_runtime.h>

#define NS 1024
#define NT 1024
#define EE 16384
#define RR 32

// ---------------------------------------------------------------------------
// Lightweight grid barrier: monotonic counter in ws (zeroed by memsetAsync
// before launch). All 256 blocks are co-resident. __threadfence() =
// agent-scope fence -> cross-XCD visibility per guide G16.
// ---------------------------------------------------------------------------
__device__ __forceinline__ void gridbar(int* cnt, int* epoch) {
    __syncthreads();
    if (threadIdx.x == 0) {
        __threadfence();                       // release our writes
        atomicAdd(cnt, 1);
        int target = 256 * (++(*epoch));
        while (__hip_atomic_load(cnt, __ATOMIC_RELAXED, __HIP_MEMORY_SCOPE_AGENT) < target)
            __builtin_amdgcn_s_sleep(2);
        __threadfence();                       // acquire others' writes
    }
    __syncthreads();
}

// One 64-lane wave handles one full softmax row (1024 cols, 16 float4/lane).
__device__ __forceinline__ void softmax_row(const float* __restrict__ Shat,
                                            float* __restrict__ outp,
                                            float* __restrict__ mrow,
                                            float* __restrict__ linv,
                                            int r, bool wout, bool wstats) {
    int ln = threadIdx.x & 63;
    const float* row = Shat + (size_t)r * 1024;
    float4 xv[4];
#pragma unroll
    for (int c = 0; c < 4; ++c) xv[c] = *(const float4*)&row[ln * 4 + c * 256];
    float m = xv[0].x;
#pragma unroll
    for (int c = 0; c < 4; ++c)
        m = fmaxf(m, fmaxf(fmaxf(xv[c].x, xv[c].y), fmaxf(xv[c].z, xv[c].w)));
#pragma unroll
    for (int off = 32; off >= 1; off >>= 1) m = fmaxf(m, __shfl_xor(m, off));
    float s = 0.f;
#pragma unroll
    for (int c = 0; c < 4; ++c) {
        xv[c].x = __expf(xv[c].x - m); xv[c].y = __expf(xv[c].y - m);
        xv[c].z = __expf(xv[c].z - m); xv[c].w = __expf(xv[c].w - m);
        s += xv[c].x + xv[c].y + xv[c].z + xv[c].w;
    }
#pragma unroll
    for (int off = 32; off >= 1; off >>= 1) s += __shfl_xor(s, off);
    float inv = 1.f / s;
    if (wout) {
        float* orow = outp + (size_t)r * 1024;
#pragma unroll
        for (int c = 0; c < 4; ++c) {
            float4 v = {xv[c].x * inv, xv[c].y * inv, xv[c].z * inv, xv[c].w * inv};
            *(float4*)&orow[ln * 4 + c * 256] = v;
        }
    }
    if (wstats && ln == 0) { mrow[r] = m; linv[r] = inv; }
}

extern "C" __global__ void __launch_bounds__(256, 1)
dgmc_fused(const float* __restrict__ X, const int* __restrict__ idx1,
           const int* __restrict__ idx2, const int* __restrict__ es,
           const int* __restrict__ et, const float* __restrict__ W1,
           const float* __restrict__ W2, const float* __restrict__ W3,
           const float* __restrict__ b3, const float* __restrict__ Wm1,
           const float* __restrict__ bm1, const float* __restrict__ Wm2,
           const float* __restrict__ bm2, const float* __restrict__ rs_all,
           float* __restrict__ out, float* __restrict__ ws) {
    const int blk = blockIdx.x, t = threadIdx.x;
    int* cnt = (int*)ws;                       // first 256 floats reserved
    float* G    = ws + 256;                    // 16384
    float* Ys   = G + 16384;                   // 131072
    float* Shat = Ys + 131072;                 // 1M
    float* mrow = Shat + (1 << 20);            // 1024
    float* linv = mrow + 1024;                 // 1024
    float* rt   = linv + 1024;                 // 32768
    float* aggs = rt + 32768;                  // 2 x 32768
    float* aggt = aggs + 65536;                // 2 x 32768
    float* Pst  = aggt + 65536;                // 2 x 32768
    int epoch = 0;

    // Max member 35,840 B -- STAY UNDER the 64 KiB per-workgroup LDS limit
    // (the 160 KiB/CU is a pool, not a per-block budget; 67.6 KB made the
    // kernel unlaunchable last round).
    __shared__ union {
        struct { float A[64][68]; float B[64][68]; } sh;                   // 34.8 KB
        struct { float P[64][36]; float U[64][36]; float O[64][36];
                 float w3[1024]; float wm1[1024]; } dl;                    // 35.8 KB
        struct { float E[256][4]; float red[8][32][4]; } rtp;              // 8 KB
        struct { float x[8][128]; } ys;                                    // 4 KB
        struct { float w[2][512]; } gr;                                    // 4 KB
    } sm;

    // ---- P1: Gram G = W1 W1^T + W2 W2^T (blocks 0..63) + zero agg bufs (64..127)
    if (blk < 64) {
        int a0 = blk * 2;
        for (int s = t; s < 1024; s += 256) {
            int r = s >> 9, c = s & 511;
            sm.gr.w[r][c] = (c < 256) ? W1[(a0 + r) * 256 + c]
                                      : W2[(a0 + r) * 256 + (c - 256)];
        }
        __syncthreads();
        int al = t >> 7, b = t & 127;
        const float4* w1b = (const float4*)(W1 + b * 256);
        const float4* w2b = (const float4*)(W2 + b * 256);
        float acc = 0.f;
        for (int c4 = 0; c4 < 64; ++c4) {
            float4 v1 = w1b[c4], v2 = w2b[c4];
            const float* wa = &sm.gr.w[al][c4 * 4];
            const float* wb = &sm.gr.w[al][256 + c4 * 4];
            acc += v1.x * wa[0] + v1.y * wa[1] + v1.z * wa[2] + v1.w * wa[3]
                 + v2.x * wb[0] + v2.y * wb[1] + v2.z * wb[2] + v2.w * wb[3];
        }
        G[(a0 + al) * 128 + b] = acc;
    } else if (blk < 128) {
        float4 z = {0.f, 0.f, 0.f, 0.f};
        float4* dst = (float4*)aggs;           // zero aggs[2] + aggt[2] = 131072 floats
        int base = (blk - 64) * 512 + t;
        dst[base] = z; dst[base + 256] = z;
    }
    gridbar(cnt, &epoch);

    // ---- P2: Ys = X[idx1] @ G (blocks 0..127) + scatter_s both steps (128..255)
    if (blk < 128) {
        int i0 = blk * 8;
        for (int s = t; s < 1024; s += 256) {
            int r = s >> 7, d = s & 127;
            sm.ys.x[r][d] = X[(size_t)idx1[i0 + r] * 128 + d];
        }
        __syncthreads();
        int a = t & 127, rp = t >> 7;
        float acc0 = 0, acc1 = 0, acc2 = 0, acc3 = 0;
        for (int d = 0; d < 128; ++d) {
            float g = G[d * 128 + a];
            acc0 += sm.ys.x[rp][d] * g;     acc1 += sm.ys.x[rp + 2][d] * g;
            acc2 += sm.ys.x[rp + 4][d] * g; acc3 += sm.ys.x[rp + 6][d] * g;
        }
        Ys[(i0 + rp) * 128 + a] = acc0;     Ys[(i0 + rp + 2) * 128 + a] = acc1;
        Ys[(i0 + rp + 4) * 128 + a] = acc2; Ys[(i0 + rp + 6) * 128 + a] = acc3;
    } else {
        int idx = blk - 128;
        int pstep = idx >> 6;
        int ebase = (idx & 63) * 256;
        const float* rsq = rs_all + pstep * (NS * RR);
        float* agg = aggs + pstep * 32768;
        int k = t & 31, eg = t >> 5;
        for (int p = 0; p < 32; ++p) {
            int e = ebase + p * 8 + eg;
            int src = es[e], d = es[EE + e];
            atomicAdd(&agg[d * 32 + k], rsq[src * 32 + k]);
        }
    }
    gridbar(cnt, &epoch);

    // ---- P3: Shat = Ys @ X[idx2]^T, 256 blocks = 16x16 tiles of 64x64,
    //      K split in two 64-wide halves to keep LDS under the 64 KB limit.
    {
        int bx = blk & 15, by = blk >> 4;
        int i0 = by * 64, j0 = bx * 64;
        int r = t >> 4, c = t & 15;
        float acc[4][4] = {};
        for (int kh = 0; kh < 2; ++kh) {
            for (int s = t; s < 64 * 16; s += 256) {
                int row = s >> 4, q = s & 15;
                *(float4*)&sm.sh.A[row][q * 4] =
                    ((const float4*)(Ys + (size_t)(i0 + row) * 128 + kh * 64))[q];
            }
            for (int s = t; s < 64 * 16; s += 256) {
                int row = s >> 4, q = s & 15;
                int src = idx2[j0 + row];
                *(float4*)&sm.sh.B[row][q * 4] =
                    ((const float4*)(X + (size_t)src * 128 + kh * 64))[q];
            }
            __syncthreads();
            for (int k = 0; k < 64; k += 4) {
                float4 ya[4], xb[4];
#pragma unroll
                for (int a = 0; a < 4; ++a) ya[a] = *(const float4*)&sm.sh.A[r + 16 * a][k];
#pragma unroll
                for (int b = 0; b < 4; ++b) xb[b] = *(const float4*)&sm.sh.B[c + 16 * b][k];
#pragma unroll
                for (int a = 0; a < 4; ++a)
#pragma unroll
                    for (int b = 0; b < 4; ++b)
                        acc[a][b] += ya[a].x * xb[b].x + ya[a].y * xb[b].y +
                                     ya[a].z * xb[b].z + ya[a].w * xb[b].w;
            }
            __syncthreads();
        }
#pragma unroll
        for (int a = 0; a < 4; ++a)
#pragma unroll
            for (int b = 0; b < 4; ++b)
                Shat[(size_t)(i0 + r + 16 * a) * 1024 + (j0 + c + 16 * b)] = acc[a][b];
    }
    gridbar(cnt, &epoch);

    for (int step = 0; step < 2; ++step) {
        const float* rsp = rs_all + step * (NS * RR);
        float* aggtp = aggt + step * 32768;
        const float* Pd = Pst + step * 32768;

        // ---- Phase A: softmax stats (+S0 out at step 0) on blocks 0..127;
        //      step 0 only: P = (relu((rs+aggs)W3+b3))Wm1+bm1 for BOTH steps on 128..255
        if (blk < 128) {
            int wv = t >> 6;
            softmax_row(Shat, out, mrow, linv, blk * 8 + wv,     step == 0, true);
            softmax_row(Shat, out, mrow, linv, blk * 8 + wv + 4, step == 0, true);
        } else if (step == 0) {
            int idx = blk - 128;
            int pstep = idx >> 6;
            int r0 = (idx & 63) * 16;
            const float* rsq = rs_all + pstep * (NS * RR);
            const float* agq = aggs + pstep * 32768;
            float* Pq = Pst + pstep * 32768;
            for (int s = t; s < 1024; s += 256) { sm.dl.w3[s] = W3[s]; sm.dl.wm1[s] = Wm1[s]; }
            int row8 = t >> 5, k = t & 31;
            float b3k = b3[k], bm1k = bm1[k];
            for (int pass = 0; pass < 2; ++pass) {
                int r = r0 + pass * 8 + row8;
                sm.dl.U[row8][k] = rsq[r * 32 + k] + agq[r * 32 + k];
                __syncthreads();
                float a1 = b3k;
#pragma unroll
                for (int m = 0; m < 32; ++m) a1 += sm.dl.U[row8][m] * sm.dl.w3[m * 32 + k];
                sm.dl.O[row8][k] = fmaxf(a1, 0.f);
                __syncthreads();
                float a2 = bm1k;
#pragma unroll
                for (int m = 0; m < 32; ++m) a2 += sm.dl.O[row8][m] * sm.dl.wm1[m * 32 + k];
                Pq[r * 32 + k] = a2;
                __syncthreads();
            }
        }
        gridbar(cnt, &epoch);

        // ---- Phase B: rt[j,k] = sum_i exp(Shat[i,j]-m_i)*linv_i * rs[i,k]
        {
            int j0 = blk * 4;
            int k = t & 31, g = t >> 5;
            float a0 = 0, a1 = 0, a2 = 0, a3 = 0;
            for (int ci = 0; ci < 4; ++ci) {
                int i = ci * 256 + t;
                float4 sv = *(const float4*)(Shat + (size_t)i * 1024 + j0);
                float mm = mrow[i], il = linv[i];
                float4 ev;
                ev.x = __expf(sv.x - mm) * il; ev.y = __expf(sv.y - mm) * il;
                ev.z = __expf(sv.z - mm) * il; ev.w = __expf(sv.w - mm) * il;
                *(float4*)&sm.rtp.E[t][0] = ev;
                __syncthreads();
                const float* rbase = rsp + (size_t)(ci * 256) * 32;
#pragma unroll 8
                for (int ii = g * 32; ii < g * 32 + 32; ++ii) {
                    float rv = rbase[ii * 32 + k];
                    float4 e4 = *(const float4*)&sm.rtp.E[ii][0];
                    a0 += e4.x * rv; a1 += e4.y * rv; a2 += e4.z * rv; a3 += e4.w * rv;
                }
                __syncthreads();
            }
            float4 av = {a0, a1, a2, a3};
            *(float4*)&sm.rtp.red[g][k][0] = av;
            __syncthreads();
            if (t < 128) {
                int j = t >> 5, kk = t & 31;
                float s = 0.f;
#pragma unroll
                for (int g2 = 0; g2 < 8; ++g2) s += sm.rtp.red[g2][kk][j];
                rt[(j0 + j) * 32 + kk] = s;
            }
        }
        gridbar(cnt, &epoch);

        // ---- Phase C: scatter_t: aggt[dst] += rt[src]
        {
            int ebase = blk * 64;
            int k = t & 31, eg = t >> 5;
#pragma unroll
            for (int p = 0; p < 8; ++p) {
                int e = ebase + p * 8 + eg;
                int src = et[e], d = et[EE + e];
                atomicAdd(&aggtp[d * 32 + k], rt[src * 32 + k]);
            }
        }
        gridbar(cnt, &epoch);

        // ---- Phase D: delta with inline Q:  Shat[i,j] += bm2 + sum_k Wm2[k]*relu(P[i,k]-Q[j,k])
        {
            int bx = blk & 15, by = blk >> 4;
            int i0 = by * 64, j0 = bx * 64;
            for (int s = t; s < 1024; s += 256) { sm.dl.w3[s] = W3[s]; sm.dl.wm1[s] = Wm1[s]; }
            int row8 = t >> 5, k = t & 31;
#pragma unroll
            for (int p = 0; p < 8; ++p) {
                int j = p * 8 + row8;
                sm.dl.U[j][k] = rt[(j0 + j) * 32 + k] + aggtp[(j0 + j) * 32 + k];
                sm.dl.P[j][k] = Pd[(i0 + j) * 32 + k];
            }
            __syncthreads();
            float b3k = b3[k];
#pragma unroll
            for (int p = 0; p < 8; ++p) {
                int j = p * 8 + row8;
                float a1 = b3k;
#pragma unroll
                for (int m = 0; m < 32; ++m) a1 += sm.dl.U[j][m] * sm.dl.w3[m * 32 + k];
                sm.dl.O[j][k] = fmaxf(a1, 0.f);
            }
            __syncthreads();
#pragma unroll
            for (int p = 0; p < 8; ++p) {      // Q overwrites U (safe: O phase synced)
                int j = p * 8 + row8;
                float a2 = 0.f;
#pragma unroll
                for (int m = 0; m < 32; ++m) a2 += sm.dl.O[j][m] * sm.dl.wm1[m * 32 + k];
                sm.dl.U[j][k] = a2;
            }
            __syncthreads();
            int r = t >> 4, c = t & 15;
            float bv = bm2[0];
            float acc[4][4] = {};
#pragma unroll
            for (int q = 0; q < 8; ++q) {
                float4 w = ((const float4*)Wm2)[q];
                float4 pa[4], qb[4];
#pragma unroll
                for (int a = 0; a < 4; ++a) pa[a] = *(const float4*)&sm.dl.P[r + 16 * a][q * 4];
#pragma unroll
                for (int b = 0; b < 4; ++b) qb[b] = *(const float4*)&sm.dl.U[c + 16 * b][q * 4];
#pragma unroll
                for (int a = 0; a < 4; ++a)
#pragma unroll
                    for (int b = 0; b < 4; ++b)
                        acc[a][b] += w.x * fmaxf(pa[a].x - qb[b].x, 0.f)
                                   + w.y * fmaxf(pa[a].y - qb[b].y, 0.f)
                                   + w.z * fmaxf(pa[a].z - qb[b].z, 0.f)
                                   + w.w * fmaxf(pa[a].w - qb[b].w, 0.f);
            }
#pragma unroll
            for (int a = 0; a < 4; ++a)
#pragma unroll
                for (int b = 0; b < 4; ++b) {
                    size_t id = (size_t)(i0 + r + 16 * a) * 1024 + (j0 + c + 16 * b);
                    Shat[id] += acc[a][b] + bv;
                }
        }
        gridbar(cnt, &epoch);
    }

    // ---- Final: S_L = softmax(Shat) -> out[1M..2M), 4 rows/block over 256 blocks
    {
        int wv = t >> 6;
        softmax_row(Shat, out + (1 << 20), mrow, linv, blk * 4 + wv, true, false);
    }
}

extern "C" void kernel_launch(void* const* d_in, const int* in_sizes, int n_in,
                              void* d_out, int out_size, void* d_ws, size_t ws_size,
                              hipStream_t stream) {
    const float* X   = (const float*)d_in[0];
    const int* idx1  = (const int*)d_in[1];
    const int* idx2  = (const int*)d_in[2];
    const int* es    = (const int*)d_in[3];
    const int* et    = (const int*)d_in[4];
    const float* W1  = (const float*)d_in[5];
    const float* W2  = (const float*)d_in[6];
    const float* W3  = (const float*)d_in[7];
    const float* b3  = (const float*)d_in[8];
    const float* Wm1 = (const float*)d_in[9];
    const float* bm1 = (const float*)d_in[10];
    const float* Wm2 = (const float*)d_in[11];
    const float* bm2 = (const float*)d_in[12];
    const float* rs  = (const float*)d_in[13];
    float* out = (float*)d_out;
    float* ws  = (float*)d_ws;

    // zero the grid-barrier counter slot (ws is poisoned 0xAA before each replay)
    hipMemsetAsync(d_ws, 0, 256, stream);

    void* args[] = {&X, &idx1, &idx2, &es, &et, &W1, &W2, &W3, &b3,
                    &Wm1, &bm1, &Wm2, &bm2, &rs, &out, &ws};
    hipError_t err = hipLaunchCooperativeKernel((const void*)dgmc_fused, dim3(256),
                                                dim3(256), args, 0, stream);
    if (err != hipSuccess) {
        // Fallback: plain launch. 256 blocks at >=1 block/CU (35.8 KB LDS,
        // __launch_bounds__(256,1)) are co-resident on 256 CUs.
        dgmc_fused<<<dim3(256), dim3(256), 0, stream>>>(
            X, idx1, idx2, es, et, W1, W2, W3, b3, Wm1, bm1, Wm2, bm2, rs, out, ws);
    }
}

// Round 4
// 420.378 us; speedup vs baseline: 1.2335x; 1.2335x over previous
//
#include <hip/hip_runtime.h>

#define NS 1024
#define NT 1024
#define EE 16384
#define RR 32

// ---------------------------------------------------------------------------
// Coherent (L1/L2-bypassing, L3-served) scalar accessors: relaxed agent-scope
// atomics compile to global_load/store_dword sc0 sc1 on gfx950. Unlike
// volatile, relaxed atomics have NO mutual-ordering waitcnt -> fully pipelined.
// ---------------------------------------------------------------------------
__device__ __forceinline__ float ldcv(const float* p) {
    return __hip_atomic_load(p, __ATOMIC_RELAXED, __HIP_MEMORY_SCOPE_AGENT);
}
__device__ __forceinline__ void stcv(float* p, float v) {
    __hip_atomic_store(p, v, __ATOMIC_RELAXED, __HIP_MEMORY_SCOPE_AGENT);
}

// ---------------------------------------------------------------------------
// Grid barrier WITHOUT cache-flush fences. Safe because all cross-block data
// is exchanged via sc0sc1 (write-through/bypass) accesses or atomics, which
// are visible at the L3 coherence point; __syncthreads() drains each wave's
// vmcnt before s_barrier (m97 asm evidence), so all block stores are complete
// before the arrival add.
// ---------------------------------------------------------------------------
__device__ __forceinline__ void gridbar(int* cnt, int* epoch) {
    __syncthreads();
    if (threadIdx.x == 0) {
        asm volatile("s_waitcnt vmcnt(0)" ::: "memory");
        __hip_atomic_fetch_add(cnt, 1, __ATOMIC_RELAXED, __HIP_MEMORY_SCOPE_AGENT);
        int target = 256 * (++(*epoch));
        while (__hip_atomic_load(cnt, __ATOMIC_RELAXED, __HIP_MEMORY_SCOPE_AGENT) < target)
            __builtin_amdgcn_s_sleep(8);
    }
    __syncthreads();
}

// One 64-lane wave handles one full softmax row (1024 cols, 16 floats/lane).
// Shat reads are coherent (ldcv); out stores are normal cached (flushed at
// kernel end); stats stores are coherent.
__device__ __forceinline__ void softmax_row(const float* __restrict__ Shat,
                                            float* __restrict__ outp,
                                            float* __restrict__ mrow,
                                            float* __restrict__ linv,
                                            int r, bool wout, bool wstats) {
    int ln = threadIdx.x & 63;
    const float* row = Shat + (size_t)r * 1024;
    float x[16];
#pragma unroll
    for (int c = 0; c < 4; ++c)
#pragma unroll
        for (int q = 0; q < 4; ++q)
            x[c * 4 + q] = ldcv(row + ln * 4 + q + c * 256);
    float m = x[0];
#pragma unroll
    for (int c = 1; c < 16; ++c) m = fmaxf(m, x[c]);
#pragma unroll
    for (int off = 32; off >= 1; off >>= 1) m = fmaxf(m, __shfl_xor(m, off));
    float s = 0.f;
#pragma unroll
    for (int c = 0; c < 16; ++c) { x[c] = __expf(x[c] - m); s += x[c]; }
#pragma unroll
    for (int off = 32; off >= 1; off >>= 1) s += __shfl_xor(s, off);
    float inv = 1.f / s;
    if (wout) {
        float* orow = outp + (size_t)r * 1024;
#pragma unroll
        for (int c = 0; c < 4; ++c) {
            float4 v = {x[c * 4] * inv, x[c * 4 + 1] * inv,
                        x[c * 4 + 2] * inv, x[c * 4 + 3] * inv};
            *(float4*)&orow[ln * 4 + c * 256] = v;
        }
    }
    if (wstats && ln == 0) { stcv(mrow + r, m); stcv(linv + r, inv); }
}

extern "C" __global__ void __launch_bounds__(256, 1)
dgmc_fused(const float* __restrict__ X, const int* __restrict__ idx1,
           const int* __restrict__ idx2, const int* __restrict__ es,
           const int* __restrict__ et, const float* __restrict__ W1,
           const float* __restrict__ W2, const float* __restrict__ W3,
           const float* __restrict__ b3, const float* __restrict__ Wm1,
           const float* __restrict__ bm1, const float* __restrict__ Wm2,
           const float* __restrict__ bm2, const float* __restrict__ rs_all,
           float* __restrict__ out, float* __restrict__ ws) {
    const int blk = blockIdx.x, t = threadIdx.x;
    int* cnt = (int*)ws;                       // first 256 floats reserved
    float* G    = ws + 256;                    // 16384
    float* Ys   = G + 16384;                   // 131072
    float* Shat = Ys + 131072;                 // 1M
    float* mrow = Shat + (1 << 20);            // 1024
    float* linv = mrow + 1024;                 // 1024
    float* rt   = linv + 1024;                 // 32768
    float* aggs = rt + 32768;                  // 2 x 32768
    float* aggt = aggs + 65536;                // 2 x 32768
    float* Pst  = aggt + 65536;                // 2 x 32768
    int epoch = 0;

    // Max member 35,840 B -- stay under the 64 KiB per-workgroup LDS limit.
    __shared__ union {
        struct { float A[64][68]; float B[64][68]; } sh;                   // 34.8 KB
        struct { float P[64][36]; float U[64][36]; float O[64][36];
                 float w3[1024]; float wm1[1024]; } dl;                    // 35.8 KB
        struct { float E[256][4]; float red[8][32][4]; } rtp;              // 8 KB
        struct { float x[8][128]; } ys;                                    // 4 KB
        struct { float w[2][512]; } gr;                                    // 4 KB
    } sm;

    // ---- P1: Gram G = W1 W1^T + W2 W2^T (blocks 0..63) + zero agg bufs (64..127)
    if (blk < 64) {
        int a0 = blk * 2;
        for (int s = t; s < 1024; s += 256) {
            int r = s >> 9, c = s & 511;
            sm.gr.w[r][c] = (c < 256) ? W1[(a0 + r) * 256 + c]
                                      : W2[(a0 + r) * 256 + (c - 256)];
        }
        __syncthreads();
        int al = t >> 7, b = t & 127;
        const float4* w1b = (const float4*)(W1 + b * 256);
        const float4* w2b = (const float4*)(W2 + b * 256);
        float acc = 0.f;
        for (int c4 = 0; c4 < 64; ++c4) {
            float4 v1 = w1b[c4], v2 = w2b[c4];
            const float* wa = &sm.gr.w[al][c4 * 4];
            const float* wb = &sm.gr.w[al][256 + c4 * 4];
            acc += v1.x * wa[0] + v1.y * wa[1] + v1.z * wa[2] + v1.w * wa[3]
                 + v2.x * wb[0] + v2.y * wb[1] + v2.z * wb[2] + v2.w * wb[3];
        }
        stcv(G + (a0 + al) * 128 + b, acc);    // coherent store (read cached later)
    } else if (blk < 128) {
        // zero aggs[2]+aggt[2] = 131072 floats, coherent stores (atomics at L3
        // must see zeros; cached-dirty zeros would be invisible to them)
        int base = ((blk - 64) * 512 + t) * 4;
#pragma unroll
        for (int q = 0; q < 4; ++q) stcv(aggs + base + q, 0.f);
#pragma unroll
        for (int q = 0; q < 4; ++q) stcv(aggs + base + 1024 + q, 0.f);
    }
    gridbar(cnt, &epoch);

    // ---- P2: Ys = X[idx1] @ G (blocks 0..127) + scatter_s both steps (128..255)
    if (blk < 128) {
        int i0 = blk * 8;
        for (int s = t; s < 1024; s += 256) {
            int r = s >> 7, d = s & 127;
            sm.ys.x[r][d] = X[(size_t)idx1[i0 + r] * 128 + d];
        }
        __syncthreads();
        int a = t & 127, rp = t >> 7;
        float acc0 = 0, acc1 = 0, acc2 = 0, acc3 = 0;
        for (int d = 0; d < 128; ++d) {
            float g = G[d * 128 + a];          // cached read: G write-once
            acc0 += sm.ys.x[rp][d] * g;     acc1 += sm.ys.x[rp + 2][d] * g;
            acc2 += sm.ys.x[rp + 4][d] * g; acc3 += sm.ys.x[rp + 6][d] * g;
        }
        stcv(Ys + (i0 + rp) * 128 + a, acc0);
        stcv(Ys + (i0 + rp + 2) * 128 + a, acc1);
        stcv(Ys + (i0 + rp + 4) * 128 + a, acc2);
        stcv(Ys + (i0 + rp + 6) * 128 + a, acc3);
    } else {
        int idx = blk - 128;
        int pstep = idx >> 6;
        int ebase = (idx & 63) * 256;
        const float* rsq = rs_all + pstep * (NS * RR);
        float* agg = aggs + pstep * 32768;
        int k = t & 31, eg = t >> 5;
        for (int p = 0; p < 32; ++p) {
            int e = ebase + p * 8 + eg;
            int src = es[e], d = es[EE + e];
            atomicAdd(&agg[d * 32 + k], rsq[src * 32 + k]);
        }
    }
    gridbar(cnt, &epoch);

    // ---- P3: Shat = Ys @ X[idx2]^T, 256 blocks = 16x16 tiles of 64x64,
    //      K split in two 64-wide halves (LDS budget).
    {
        int bx = blk & 15, by = blk >> 4;
        int i0 = by * 64, j0 = bx * 64;
        int r = t >> 4, c = t & 15;
        float acc[4][4] = {};
        for (int kh = 0; kh < 2; ++kh) {
            for (int s = t; s < 64 * 16; s += 256) {
                int row = s >> 4, q = s & 15;
                *(float4*)&sm.sh.A[row][q * 4] =
                    ((const float4*)(Ys + (size_t)(i0 + row) * 128 + kh * 64))[q];
            }
            for (int s = t; s < 64 * 16; s += 256) {
                int row = s >> 4, q = s & 15;
                int src = idx2[j0 + row];
                *(float4*)&sm.sh.B[row][q * 4] =
                    ((const float4*)(X + (size_t)src * 128 + kh * 64))[q];
            }
            __syncthreads();
            for (int k = 0; k < 64; k += 4) {
                float4 ya[4], xb[4];
#pragma unroll
                for (int a = 0; a < 4; ++a) ya[a] = *(const float4*)&sm.sh.A[r + 16 * a][k];
#pragma unroll
                for (int b = 0; b < 4; ++b) xb[b] = *(const float4*)&sm.sh.B[c + 16 * b][k];
#pragma unroll
                for (int a = 0; a < 4; ++a)
#pragma unroll
                    for (int b = 0; b < 4; ++b)
                        acc[a][b] += ya[a].x * xb[b].x + ya[a].y * xb[b].y +
                                     ya[a].z * xb[b].z + ya[a].w * xb[b].w;
            }
            __syncthreads();
        }
#pragma unroll
        for (int a = 0; a < 4; ++a)
#pragma unroll
            for (int b = 0; b < 4; ++b)
                stcv(Shat + (size_t)(i0 + r + 16 * a) * 1024 + (j0 + c + 16 * b),
                     acc[a][b]);
    }
    gridbar(cnt, &epoch);

    for (int step = 0; step < 2; ++step) {
        const float* rsp = rs_all + step * (NS * RR);
        float* aggtp = aggt + step * 32768;
        const float* Pd = Pst + step * 32768;

        // ---- Phase A: softmax stats (+S0 out at step 0) on blocks 0..127;
        //      step 0 only: P = (relu((rs+aggs)W3+b3))Wm1+bm1 for BOTH steps on 128..255
        if (blk < 128) {
            int wv = t >> 6;
            softmax_row(Shat, out, mrow, linv, blk * 8 + wv,     step == 0, true);
            softmax_row(Shat, out, mrow, linv, blk * 8 + wv + 4, step == 0, true);
        } else if (step == 0) {
            int idx = blk - 128;
            int pstep = idx >> 6;
            int r0 = (idx & 63) * 16;
            const float* rsq = rs_all + pstep * (NS * RR);
            const float* agq = aggs + pstep * 32768;
            float* Pq = Pst + pstep * 32768;
            for (int s = t; s < 1024; s += 256) { sm.dl.w3[s] = W3[s]; sm.dl.wm1[s] = Wm1[s]; }
            int row8 = t >> 5, k = t & 31;
            float b3k = b3[k], bm1k = bm1[k];
            for (int pass = 0; pass < 2; ++pass) {
                int r = r0 + pass * 8 + row8;
                sm.dl.U[row8][k] = rsq[r * 32 + k] + ldcv(agq + r * 32 + k);
                __syncthreads();
                float a1 = b3k;
#pragma unroll
                for (int m = 0; m < 32; ++m) a1 += sm.dl.U[row8][m] * sm.dl.w3[m * 32 + k];
                sm.dl.O[row8][k] = fmaxf(a1, 0.f);
                __syncthreads();
                float a2 = bm1k;
#pragma unroll
                for (int m = 0; m < 32; ++m) a2 += sm.dl.O[row8][m] * sm.dl.wm1[m * 32 + k];
                stcv(Pq + r * 32 + k, a2);
                __syncthreads();
            }
        }
        gridbar(cnt, &epoch);

        // ---- Phase B: rt[j,k] = sum_i exp(Shat[i,j]-m_i)*linv_i * rs[i,k]
        {
            int j0 = blk * 4;
            int k = t & 31, g = t >> 5;
            float a0 = 0, a1 = 0, a2 = 0, a3 = 0;
            for (int ci = 0; ci < 4; ++ci) {
                int i = ci * 256 + t;
                float s0 = ldcv(Shat + (size_t)i * 1024 + j0);
                float s1 = ldcv(Shat + (size_t)i * 1024 + j0 + 1);
                float s2 = ldcv(Shat + (size_t)i * 1024 + j0 + 2);
                float s3 = ldcv(Shat + (size_t)i * 1024 + j0 + 3);
                float mm = ldcv(mrow + i), il = ldcv(linv + i);
                float4 ev;
                ev.x = __expf(s0 - mm) * il; ev.y = __expf(s1 - mm) * il;
                ev.z = __expf(s2 - mm) * il; ev.w = __expf(s3 - mm) * il;
                *(float4*)&sm.rtp.E[t][0] = ev;
                __syncthreads();
                const float* rbase = rsp + (size_t)(ci * 256) * 32;
#pragma unroll 8
                for (int ii = g * 32; ii < g * 32 + 32; ++ii) {
                    float rv = rbase[ii * 32 + k];
                    float4 e4 = *(const float4*)&sm.rtp.E[ii][0];
                    a0 += e4.x * rv; a1 += e4.y * rv; a2 += e4.z * rv; a3 += e4.w * rv;
                }
                __syncthreads();
            }
            float4 av = {a0, a1, a2, a3};
            *(float4*)&sm.rtp.red[g][k][0] = av;
            __syncthreads();
            if (t < 128) {
                int j = t >> 5, kk = t & 31;
                float s = 0.f;
#pragma unroll
                for (int g2 = 0; g2 < 8; ++g2) s += sm.rtp.red[g2][kk][j];
                stcv(rt + (j0 + j) * 32 + kk, s);
            }
        }
        gridbar(cnt, &epoch);

        // ---- Phase C: scatter_t: aggt[dst] += rt[src]
        {
            int ebase = blk * 64;
            int k = t & 31, eg = t >> 5;
#pragma unroll
            for (int p = 0; p < 8; ++p) {
                int e = ebase + p * 8 + eg;
                int src = et[e], d = et[EE + e];
                atomicAdd(&aggtp[d * 32 + k], ldcv(rt + src * 32 + k));
            }
        }
        gridbar(cnt, &epoch);

        // ---- Phase D: delta with inline Q: Shat[i,j] += bm2 + sum_k Wm2[k]*relu(P[i,k]-Q[j,k])
        {
            int bx = blk & 15, by = blk >> 4;
            int i0 = by * 64, j0 = bx * 64;
            for (int s = t; s < 1024; s += 256) { sm.dl.w3[s] = W3[s]; sm.dl.wm1[s] = Wm1[s]; }
            int row8 = t >> 5, k = t & 31;
#pragma unroll
            for (int p = 0; p < 8; ++p) {
                int j = p * 8 + row8;
                sm.dl.U[j][k] = ldcv(rt + (j0 + j) * 32 + k) + ldcv(aggtp + (j0 + j) * 32 + k);
                sm.dl.P[j][k] = Pd[(i0 + j) * 32 + k];   // cached: Pst write-once
            }
            __syncthreads();
            float b3k = b3[k];
#pragma unroll
            for (int p = 0; p < 8; ++p) {
                int j = p * 8 + row8;
                float a1 = b3k;
#pragma unroll
                for (int m = 0; m < 32; ++m) a1 += sm.dl.U[j][m] * sm.dl.w3[m * 32 + k];
                sm.dl.O[j][k] = fmaxf(a1, 0.f);
            }
            __syncthreads();
#pragma unroll
            for (int p = 0; p < 8; ++p) {      // Q overwrites U (safe: O phase synced)
                int j = p * 8 + row8;
                float a2 = 0.f;
#pragma unroll
                for (int m = 0; m < 32; ++m) a2 += sm.dl.O[j][m] * sm.dl.wm1[m * 32 + k];
                sm.dl.U[j][k] = a2;
            }
            __syncthreads();
            int r = t >> 4, c = t & 15;
            float bv = bm2[0];
            float acc[4][4] = {};
#pragma unroll
            for (int q = 0; q < 8; ++q) {
                float4 w = ((const float4*)Wm2)[q];
                float4 pa[4], qb[4];
#pragma unroll
                for (int a = 0; a < 4; ++a) pa[a] = *(const float4*)&sm.dl.P[r + 16 * a][q * 4];
#pragma unroll
                for (int b = 0; b < 4; ++b) qb[b] = *(const float4*)&sm.dl.U[c + 16 * b][q * 4];
#pragma unroll
                for (int a = 0; a < 4; ++a)
#pragma unroll
                    for (int b = 0; b < 4; ++b)
                        acc[a][b] += w.x * fmaxf(pa[a].x - qb[b].x, 0.f)
                                   + w.y * fmaxf(pa[a].y - qb[b].y, 0.f)
                                   + w.z * fmaxf(pa[a].z - qb[b].z, 0.f)
                                   + w.w * fmaxf(pa[a].w - qb[b].w, 0.f);
            }
#pragma unroll
            for (int a = 0; a < 4; ++a)
#pragma unroll
                for (int b = 0; b < 4; ++b) {
                    float* p = Shat + (size_t)(i0 + r + 16 * a) * 1024 + (j0 + c + 16 * b);
                    stcv(p, ldcv(p) + acc[a][b] + bv);
                }
        }
        gridbar(cnt, &epoch);
    }

    // ---- Final: S_L = softmax(Shat) -> out[1M..2M), 4 rows/block over 256 blocks
    {
        int wv = t >> 6;
        softmax_row(Shat, out + (1 << 20), mrow, linv, blk * 4 + wv, true, false);
    }
}

extern "C" void kernel_launch(void* const* d_in, const int* in_sizes, int n_in,
                              void* d_out, int out_size, void* d_ws, size_t ws_size,
                              hipStream_t stream) {
    const float* X   = (const float*)d_in[0];
    const int* idx1  = (const int*)d_in[1];
    const int* idx2  = (const int*)d_in[2];
    const int* es    = (const int*)d_in[3];
    const int* et    = (const int*)d_in[4];
    const float* W1  = (const float*)d_in[5];
    const float* W2  = (const float*)d_in[6];
    const float* W3  = (const float*)d_in[7];
    const float* b3  = (const float*)d_in[8];
    const float* Wm1 = (const float*)d_in[9];
    const float* bm1 = (const float*)d_in[10];
    const float* Wm2 = (const float*)d_in[11];
    const float* bm2 = (const float*)d_in[12];
    const float* rs  = (const float*)d_in[13];
    float* out = (float*)d_out;
    float* ws  = (float*)d_ws;

    // zero the grid-barrier counter slot (ws is poisoned 0xAA before each replay)
    hipMemsetAsync(d_ws, 0, 256, stream);

    void* args[] = {&X, &idx1, &idx2, &es, &et, &W1, &W2, &W3, &b3,
                    &Wm1, &bm1, &Wm2, &bm2, &rs, &out, &ws};
    hipError_t err = hipLaunchCooperativeKernel((const void*)dgmc_fused, dim3(256),
                                                dim3(256), args, 0, stream);
    if (err != hipSuccess) {
        // Fallback: plain launch. 256 blocks at 1 block/CU (35.8 KB LDS,
        // __launch_bounds__(256,1)) are co-resident on 256 CUs.
        dgmc_fused<<<dim3(256), dim3(256), 0, stream>>>(
            X, idx1, idx2, es, et, W1, W2, W3, b3, Wm1, bm1, Wm2, bm2, rs, out, ws);
    }
}

// Round 5
// 374.033 us; speedup vs baseline: 1.3864x; 1.1239x over previous
//
#include <hip/hip_runtime.h>

#define NS 1024
#define NT 1024
#define EE 16384
#define RR 32

// ---------------------------------------------------------------------------
// Coherent (L1/L2-bypassing, L3-served) scalar accessors: relaxed agent-scope
// atomics compile to global_load/store_dword sc0 sc1 on gfx950.
// ---------------------------------------------------------------------------
__device__ __forceinline__ float ldcv(const float* p) {
    return __hip_atomic_load(p, __ATOMIC_RELAXED, __HIP_MEMORY_SCOPE_AGENT);
}
__device__ __forceinline__ void stcv(float* p, float v) {
    __hip_atomic_store(p, v, __ATOMIC_RELAXED, __HIP_MEMORY_SCOPE_AGENT);
}

// ---------------------------------------------------------------------------
// Distributed-flag grid barrier. Arrival: one fetch_add per block on a single
// line -- but NOBODY polls that line; the last arriver detects completion from
// its own fetch_add return value and broadcasts the epoch to 256 PRIVATE
// 64B-spaced flag lines (one store per thread). Each waiting block's lane 0
// polls only its own flag line -> no same-line contention, no poll storm
// (the R4 barrier's counter line took ~1200 same-line txn/us and collapsed).
// Epochs are monotone; per-location coherence orders flag updates, so no
// re-zeroing between barriers. cnt+flags zeroed by host memsetAsync.
// ---------------------------------------------------------------------------
__device__ __forceinline__ void gridbar(int* cnt, int* flags, int* epoch,
                                        int* s_last, int blk) {
    int e = ++(*epoch);
    __syncthreads();
    if (threadIdx.x == 0) {
        asm volatile("s_waitcnt vmcnt(0)" ::: "memory");   // drain our stores
        int old = __hip_atomic_fetch_add(cnt, 1, __ATOMIC_RELAXED,
                                         __HIP_MEMORY_SCOPE_AGENT);
        *s_last = (old == 256 * e - 1) ? 1 : 0;
    }
    __syncthreads();
    if (*s_last) {
        // we are the release block: signal every block's private flag line
        __hip_atomic_store(flags + (int)threadIdx.x * 16, e, __ATOMIC_RELAXED,
                           __HIP_MEMORY_SCOPE_AGENT);
    } else if (threadIdx.x == 0) {
        while (__hip_atomic_load(flags + blk * 16, __ATOMIC_RELAXED,
                                 __HIP_MEMORY_SCOPE_AGENT) < e)
            __builtin_amdgcn_s_sleep(2);
    }
    __syncthreads();
}

// One 64-lane wave handles one full softmax row (1024 cols, 16 floats/lane).
__device__ __forceinline__ void softmax_row(const float* __restrict__ Shat,
                                            float* __restrict__ outp,
                                            float* __restrict__ mrow,
                                            float* __restrict__ linv,
                                            int r, bool wout, bool wstats) {
    int ln = threadIdx.x & 63;
    const float* row = Shat + (size_t)r * 1024;
    float x[16];
#pragma unroll
    for (int c = 0; c < 4; ++c)
#pragma unroll
        for (int q = 0; q < 4; ++q)
            x[c * 4 + q] = ldcv(row + ln * 4 + q + c * 256);
    float m = x[0];
#pragma unroll
    for (int c = 1; c < 16; ++c) m = fmaxf(m, x[c]);
#pragma unroll
    for (int off = 32; off >= 1; off >>= 1) m = fmaxf(m, __shfl_xor(m, off));
    float s = 0.f;
#pragma unroll
    for (int c = 0; c < 16; ++c) { x[c] = __expf(x[c] - m); s += x[c]; }
#pragma unroll
    for (int off = 32; off >= 1; off >>= 1) s += __shfl_xor(s, off);
    float inv = 1.f / s;
    if (wout) {
        float* orow = outp + (size_t)r * 1024;
#pragma unroll
        for (int c = 0; c < 4; ++c) {
            float4 v = {x[c * 4] * inv, x[c * 4 + 1] * inv,
                        x[c * 4 + 2] * inv, x[c * 4 + 3] * inv};
            *(float4*)&orow[ln * 4 + c * 256] = v;
        }
    }
    if (wstats && ln == 0) { stcv(mrow + r, m); stcv(linv + r, inv); }
}

extern "C" __global__ void __launch_bounds__(256, 1)
dgmc_fused(const float* __restrict__ X, const int* __restrict__ idx1,
           const int* __restrict__ idx2, const int* __restrict__ es,
           const int* __restrict__ et, const float* __restrict__ W1,
           const float* __restrict__ W2, const float* __restrict__ W3,
           const float* __restrict__ b3, const float* __restrict__ Wm1,
           const float* __restrict__ bm1, const float* __restrict__ Wm2,
           const float* __restrict__ bm2, const float* __restrict__ rs_all,
           float* __restrict__ out, float* __restrict__ ws) {
    const int blk = blockIdx.x, t = threadIdx.x;
    // int header (zeroed by host memset, 32 KB): cnt line + 256 flag lines
    int* cnt   = (int*)ws;                     // ws[0], own 64B line
    int* flags = (int*)ws + 16;                // flags[b] at +b*16 ints (64B apart)
    float* G    = ws + 8192;                   // 16384
    float* Ys   = G + 16384;                   // 131072
    float* Shat = Ys + 131072;                 // 1M
    float* mrow = Shat + (1 << 20);            // 1024
    float* linv = mrow + 1024;                 // 1024
    float* rt   = linv + 1024;                 // 32768
    float* aggs = rt + 32768;                  // 2 x 32768
    float* aggt = aggs + 65536;                // 2 x 32768
    float* Pst  = aggt + 65536;                // 2 x 32768
    int epoch = 0;
    __shared__ int s_last;

    // Max member 35,840 B -- stay under the 64 KiB per-workgroup LDS limit.
    __shared__ union {
        struct { float A[64][68]; float B[64][68]; } sh;                   // 34.8 KB
        struct { float P[64][36]; float U[64][36]; float O[64][36];
                 float w3[1024]; float wm1[1024]; } dl;                    // 35.8 KB
        struct { float E[256][4]; float red[8][32][4]; } rtp;              // 8 KB
        struct { float x[8][128]; } ys;                                    // 4 KB
        struct { float w[2][512]; } gr;                                    // 4 KB
    } sm;

    // ---- P1: Gram G = W1 W1^T + W2 W2^T (blocks 0..63) + zero agg bufs (64..127)
    if (blk < 64) {
        int a0 = blk * 2;
        for (int s = t; s < 1024; s += 256) {
            int r = s >> 9, c = s & 511;
            sm.gr.w[r][c] = (c < 256) ? W1[(a0 + r) * 256 + c]
                                      : W2[(a0 + r) * 256 + (c - 256)];
        }
        __syncthreads();
        int al = t >> 7, b = t & 127;
        const float4* w1b = (const float4*)(W1 + b * 256);
        const float4* w2b = (const float4*)(W2 + b * 256);
        float acc = 0.f;
        for (int c4 = 0; c4 < 64; ++c4) {
            float4 v1 = w1b[c4], v2 = w2b[c4];
            const float* wa = &sm.gr.w[al][c4 * 4];
            const float* wb = &sm.gr.w[al][256 + c4 * 4];
            acc += v1.x * wa[0] + v1.y * wa[1] + v1.z * wa[2] + v1.w * wa[3]
                 + v2.x * wb[0] + v2.y * wb[1] + v2.z * wb[2] + v2.w * wb[3];
        }
        stcv(G + (a0 + al) * 128 + b, acc);    // coherent store (read cached later)
    } else if (blk < 128) {
        // zero aggs[2]+aggt[2] = 131072 floats via coherent stores
        int base = ((blk - 64) * 512 + t) * 4;
#pragma unroll
        for (int q = 0; q < 4; ++q) stcv(aggs + base + q, 0.f);
#pragma unroll
        for (int q = 0; q < 4; ++q) stcv(aggs + base + 1024 + q, 0.f);
    }
    gridbar(cnt, flags, &epoch, &s_last, blk);

    // ---- P2: Ys = X[idx1] @ G (blocks 0..127) + scatter_s both steps (128..255)
    if (blk < 128) {
        int i0 = blk * 8;
        for (int s = t; s < 1024; s += 256) {
            int r = s >> 7, d = s & 127;
            sm.ys.x[r][d] = X[(size_t)idx1[i0 + r] * 128 + d];
        }
        __syncthreads();
        int a = t & 127, rp = t >> 7;
        float acc0 = 0, acc1 = 0, acc2 = 0, acc3 = 0;
        for (int d = 0; d < 128; ++d) {
            float g = G[d * 128 + a];          // cached read: G write-once
            acc0 += sm.ys.x[rp][d] * g;     acc1 += sm.ys.x[rp + 2][d] * g;
            acc2 += sm.ys.x[rp + 4][d] * g; acc3 += sm.ys.x[rp + 6][d] * g;
        }
        stcv(Ys + (i0 + rp) * 128 + a, acc0);
        stcv(Ys + (i0 + rp + 2) * 128 + a, acc1);
        stcv(Ys + (i0 + rp + 4) * 128 + a, acc2);
        stcv(Ys + (i0 + rp + 6) * 128 + a, acc3);
    } else {
        int idx = blk - 128;
        int pstep = idx >> 6;
        int ebase = (idx & 63) * 256;
        const float* rsq = rs_all + pstep * (NS * RR);
        float* agg = aggs + pstep * 32768;
        int k = t & 31, eg = t >> 5;
        for (int p = 0; p < 32; ++p) {
            int e = ebase + p * 8 + eg;
            int src = es[e], d = es[EE + e];
            atomicAdd(&agg[d * 32 + k], rsq[src * 32 + k]);
        }
    }
    gridbar(cnt, flags, &epoch, &s_last, blk);

    // ---- P3: Shat = Ys @ X[idx2]^T, 256 blocks = 16x16 tiles of 64x64,
    //      K split in two 64-wide halves (LDS budget).
    {
        int bx = blk & 15, by = blk >> 4;
        int i0 = by * 64, j0 = bx * 64;
        int r = t >> 4, c = t & 15;
        float acc[4][4] = {};
        for (int kh = 0; kh < 2; ++kh) {
            for (int s = t; s < 64 * 16; s += 256) {
                int row = s >> 4, q = s & 15;
                *(float4*)&sm.sh.A[row][q * 4] =
                    ((const float4*)(Ys + (size_t)(i0 + row) * 128 + kh * 64))[q];
            }
            for (int s = t; s < 64 * 16; s += 256) {
                int row = s >> 4, q = s & 15;
                int src = idx2[j0 + row];
                *(float4*)&sm.sh.B[row][q * 4] =
                    ((const float4*)(X + (size_t)src * 128 + kh * 64))[q];
            }
            __syncthreads();
            for (int k = 0; k < 64; k += 4) {
                float4 ya[4], xb[4];
#pragma unroll
                for (int a = 0; a < 4; ++a) ya[a] = *(const float4*)&sm.sh.A[r + 16 * a][k];
#pragma unroll
                for (int b = 0; b < 4; ++b) xb[b] = *(const float4*)&sm.sh.B[c + 16 * b][k];
#pragma unroll
                for (int a = 0; a < 4; ++a)
#pragma unroll
                    for (int b = 0; b < 4; ++b)
                        acc[a][b] += ya[a].x * xb[b].x + ya[a].y * xb[b].y +
                                     ya[a].z * xb[b].z + ya[a].w * xb[b].w;
            }
            __syncthreads();
        }
#pragma unroll
        for (int a = 0; a < 4; ++a)
#pragma unroll
            for (int b = 0; b < 4; ++b)
                stcv(Shat + (size_t)(i0 + r + 16 * a) * 1024 + (j0 + c + 16 * b),
                     acc[a][b]);
    }
    gridbar(cnt, flags, &epoch, &s_last, blk);

    for (int step = 0; step < 2; ++step) {
        const float* rsp = rs_all + step * (NS * RR);
        float* aggtp = aggt + step * 32768;
        const float* Pd = Pst + step * 32768;

        // ---- Phase A: softmax stats (+S0 out at step 0) on blocks 0..127;
        //      step 0 only: P = (relu((rs+aggs)W3+b3))Wm1+bm1 for BOTH steps on 128..255
        if (blk < 128) {
            int wv = t >> 6;
            softmax_row(Shat, out, mrow, linv, blk * 8 + wv,     step == 0, true);
            softmax_row(Shat, out, mrow, linv, blk * 8 + wv + 4, step == 0, true);
        } else if (step == 0) {
            int idx = blk - 128;
            int pstep = idx >> 6;
            int r0 = (idx & 63) * 16;
            const float* rsq = rs_all + pstep * (NS * RR);
            const float* agq = aggs + pstep * 32768;
            float* Pq = Pst + pstep * 32768;
            for (int s = t; s < 1024; s += 256) { sm.dl.w3[s] = W3[s]; sm.dl.wm1[s] = Wm1[s]; }
            int row8 = t >> 5, k = t & 31;
            float b3k = b3[k], bm1k = bm1[k];
            for (int pass = 0; pass < 2; ++pass) {
                int r = r0 + pass * 8 + row8;
                sm.dl.U[row8][k] = rsq[r * 32 + k] + ldcv(agq + r * 32 + k);
                __syncthreads();
                float a1 = b3k;
#pragma unroll
                for (int m = 0; m < 32; ++m) a1 += sm.dl.U[row8][m] * sm.dl.w3[m * 32 + k];
                sm.dl.O[row8][k] = fmaxf(a1, 0.f);
                __syncthreads();
                float a2 = bm1k;
#pragma unroll
                for (int m = 0; m < 32; ++m) a2 += sm.dl.O[row8][m] * sm.dl.wm1[m * 32 + k];
                stcv(Pq + r * 32 + k, a2);
                __syncthreads();
            }
        }
        gridbar(cnt, flags, &epoch, &s_last, blk);

        // ---- Phase B: rt[j,k] = sum_i exp(Shat[i,j]-m_i)*linv_i * rs[i,k]
        {
            int j0 = blk * 4;
            int k = t & 31, g = t >> 5;
            float a0 = 0, a1 = 0, a2 = 0, a3 = 0;
            for (int ci = 0; ci < 4; ++ci) {
                int i = ci * 256 + t;
                float s0 = ldcv(Shat + (size_t)i * 1024 + j0);
                float s1 = ldcv(Shat + (size_t)i * 1024 + j0 + 1);
                float s2 = ldcv(Shat + (size_t)i * 1024 + j0 + 2);
                float s3 = ldcv(Shat + (size_t)i * 1024 + j0 + 3);
                float mm = ldcv(mrow + i), il = ldcv(linv + i);
                float4 ev;
                ev.x = __expf(s0 - mm) * il; ev.y = __expf(s1 - mm) * il;
                ev.z = __expf(s2 - mm) * il; ev.w = __expf(s3 - mm) * il;
                *(float4*)&sm.rtp.E[t][0] = ev;
                __syncthreads();
                const float* rbase = rsp + (size_t)(ci * 256) * 32;
#pragma unroll 8
                for (int ii = g * 32; ii < g * 32 + 32; ++ii) {
                    float rv = rbase[ii * 32 + k];
                    float4 e4 = *(const float4*)&sm.rtp.E[ii][0];
                    a0 += e4.x * rv; a1 += e4.y * rv; a2 += e4.z * rv; a3 += e4.w * rv;
                }
                __syncthreads();
            }
            float4 av = {a0, a1, a2, a3};
            *(float4*)&sm.rtp.red[g][k][0] = av;
            __syncthreads();
            if (t < 128) {
                int j = t >> 5, kk = t & 31;
                float s = 0.f;
#pragma unroll
                for (int g2 = 0; g2 < 8; ++g2) s += sm.rtp.red[g2][kk][j];
                stcv(rt + (j0 + j) * 32 + kk, s);
            }
        }
        gridbar(cnt, flags, &epoch, &s_last, blk);

        // ---- Phase C: scatter_t: aggt[dst] += rt[src]
        {
            int ebase = blk * 64;
            int k = t & 31, eg = t >> 5;
#pragma unroll
            for (int p = 0; p < 8; ++p) {
                int e = ebase + p * 8 + eg;
                int src = et[e], d = et[EE + e];
                atomicAdd(&aggtp[d * 32 + k], ldcv(rt + src * 32 + k));
            }
        }
        gridbar(cnt, flags, &epoch, &s_last, blk);

        // ---- Phase D: delta with inline Q: Shat[i,j] += bm2 + sum_k Wm2[k]*relu(P[i,k]-Q[j,k])
        {
            int bx = blk & 15, by = blk >> 4;
            int i0 = by * 64, j0 = bx * 64;
            for (int s = t; s < 1024; s += 256) { sm.dl.w3[s] = W3[s]; sm.dl.wm1[s] = Wm1[s]; }
            int row8 = t >> 5, k = t & 31;
#pragma unroll
            for (int p = 0; p < 8; ++p) {
                int j = p * 8 + row8;
                sm.dl.U[j][k] = ldcv(rt + (j0 + j) * 32 + k) + ldcv(aggtp + (j0 + j) * 32 + k);
                sm.dl.P[j][k] = Pd[(i0 + j) * 32 + k];   // cached: Pst write-once
            }
            __syncthreads();
            float b3k = b3[k];
#pragma unroll
            for (int p = 0; p < 8; ++p) {
                int j = p * 8 + row8;
                float a1 = b3k;
#pragma unroll
                for (int m = 0; m < 32; ++m) a1 += sm.dl.U[j][m] * sm.dl.w3[m * 32 + k];
                sm.dl.O[j][k] = fmaxf(a1, 0.f);
            }
            __syncthreads();
#pragma unroll
            for (int p = 0; p < 8; ++p) {      // Q overwrites U (safe: O phase synced)
                int j = p * 8 + row8;
                float a2 = 0.f;
#pragma unroll
                for (int m = 0; m < 32; ++m) a2 += sm.dl.O[j][m] * sm.dl.wm1[m * 32 + k];
                sm.dl.U[j][k] = a2;
            }
            __syncthreads();
            int r = t >> 4, c = t & 15;
            float bv = bm2[0];
            float acc[4][4] = {};
#pragma unroll
            for (int q = 0; q < 8; ++q) {
                float4 w = ((const float4*)Wm2)[q];
                float4 pa[4], qb[4];
#pragma unroll
                for (int a = 0; a < 4; ++a) pa[a] = *(const float4*)&sm.dl.P[r + 16 * a][q * 4];
#pragma unroll
                for (int b = 0; b < 4; ++b) qb[b] = *(const float4*)&sm.dl.U[c + 16 * b][q * 4];
#pragma unroll
                for (int a = 0; a < 4; ++a)
#pragma unroll
                    for (int b = 0; b < 4; ++b)
                        acc[a][b] += w.x * fmaxf(pa[a].x - qb[b].x, 0.f)
                                   + w.y * fmaxf(pa[a].y - qb[b].y, 0.f)
                                   + w.z * fmaxf(pa[a].z - qb[b].z, 0.f)
                                   + w.w * fmaxf(pa[a].w - qb[b].w, 0.f);
            }
#pragma unroll
            for (int a = 0; a < 4; ++a)
#pragma unroll
                for (int b = 0; b < 4; ++b) {
                    float* p = Shat + (size_t)(i0 + r + 16 * a) * 1024 + (j0 + c + 16 * b);
                    stcv(p, ldcv(p) + acc[a][b] + bv);
                }
        }
        gridbar(cnt, flags, &epoch, &s_last, blk);
    }

    // ---- Final: S_L = softmax(Shat) -> out[1M..2M), 4 rows/block over 256 blocks
    {
        int wv = t >> 6;
        softmax_row(Shat, out + (1 << 20), mrow, linv, blk * 4 + wv, true, false);
    }
}

extern "C" void kernel_launch(void* const* d_in, const int* in_sizes, int n_in,
                              void* d_out, int out_size, void* d_ws, size_t ws_size,
                              hipStream_t stream) {
    const float* X   = (const float*)d_in[0];
    const int* idx1  = (const int*)d_in[1];
    const int* idx2  = (const int*)d_in[2];
    const int* es    = (const int*)d_in[3];
    const int* et    = (const int*)d_in[4];
    const float* W1  = (const float*)d_in[5];
    const float* W2  = (const float*)d_in[6];
    const float* W3  = (const float*)d_in[7];
    const float* b3  = (const float*)d_in[8];
    const float* Wm1 = (const float*)d_in[9];
    const float* bm1 = (const float*)d_in[10];
    const float* Wm2 = (const float*)d_in[11];
    const float* bm2 = (const float*)d_in[12];
    const float* rs  = (const float*)d_in[13];
    float* out = (float*)d_out;
    float* ws  = (float*)d_ws;

    // zero the barrier header: cnt line + 256 private flag lines (32 KB)
    hipMemsetAsync(d_ws, 0, 32768, stream);

    void* args[] = {&X, &idx1, &idx2, &es, &et, &W1, &W2, &W3, &b3,
                    &Wm1, &bm1, &Wm2, &bm2, &rs, &out, &ws};
    hipError_t err = hipLaunchCooperativeKernel((const void*)dgmc_fused, dim3(256),
                                                dim3(256), args, 0, stream);
    if (err != hipSuccess) {
        // Fallback: plain launch. 256 blocks at 1 block/CU (35.8 KB LDS,
        // __launch_bounds__(256,1)) are co-resident on 256 CUs.
        dgmc_fused<<<dim3(256), dim3(256), 0, stream>>>(
            X, idx1, idx2, es, et, W1, W2, W3, b3, Wm1, bm1, Wm2, bm2, rs, out, ws);
    }
}